// Round 5
// baseline (149.892 us; speedup 1.0000x reference)
//
#include <hip/hip_runtime.h>

typedef unsigned short ushort_t;
typedef __bf16 bf16x8 __attribute__((ext_vector_type(8)));
typedef float f32x4 __attribute__((ext_vector_type(4)));
typedef float f32x16 __attribute__((ext_vector_type(16)));

#define DEVI __device__ __forceinline__

constexpr int BSZ = 4;     // batch
constexpr int MDIM = 190;  // axial dim
constexpr int TDIM = 512;  // seq
constexpr int CDIM = 64;   // channels

DEVI ushort_t f2bf(float f) {
    union { float f; unsigned int u; } v; v.f = f;
    unsigned int u = v.u;
    u += 0x7FFFu + ((u >> 16) & 1u);   // round-to-nearest-even
    return (ushort_t)(u >> 16);
}

// ---------------------------------------------------------------- K1: fused v-projection + xsum partials
__global__ __launch_bounds__(256, 4) void k_vproj(const float* __restrict__ x,
                                                  const float* __restrict__ Wv,
                                                  const float* __restrict__ bv,
                                                  ushort_t* __restrict__ vt,
                                                  float* __restrict__ xsp) {
    __shared__ __align__(16) ushort_t xbf[64 * 72];
    __shared__ __align__(16) ushort_t WvT[64 * 72];
    __shared__ __align__(16) ushort_t vst[64 * 72];

    int tid = threadIdx.x;
    int bid = blockIdx.x;            // 512 = 4b * 8tt * 16mg
    int mg = bid & 15;
    int tt = (bid >> 4) & 7;
    int b = bid >> 7;
    int t0 = tt * 64;
    int mbase = mg * 12;
    int cnt = (mbase + 12 <= MDIM) ? 12 : (MDIM - mbase);   // 12 or 10

    int w = tid >> 6, lane = tid & 63;
    int la = lane & 15, lb = lane >> 4;
    int r = tid >> 2, seg = tid & 3;

#pragma unroll
    for (int rep = 0; rep < 16; ++rep) {
        int j = rep * 256 + tid;
        int ci = j >> 6, co = j & 63;
        WvT[co * 72 + ci] = f2bf(Wv[j]);
    }
    float bvv[4];
#pragma unroll
    for (int cf = 0; cf < 4; ++cf) bvv[cf] = bv[16 * cf + la];

    float xacc[16];
#pragma unroll
    for (int u = 0; u < 16; ++u) xacc[u] = 0.f;

    const size_t mstride = (size_t)TDIM * CDIM;  // 32768
    size_t xaddr = ((size_t)(b * MDIM + mbase) * TDIM + t0 + r) * CDIM + seg * 16;

    float4 xv[4];
#pragma unroll
    for (int u = 0; u < 4; ++u) xv[u] = *(const float4*)(x + xaddr + u * 4);

    f32x4 zz = {0.f, 0.f, 0.f, 0.f};

    for (int i = 0; i < cnt; ++i) {
#pragma unroll
        for (int u = 0; u < 4; ++u) {
            xacc[u * 4 + 0] += xv[u].x;
            xacc[u * 4 + 1] += xv[u].y;
            xacc[u * 4 + 2] += xv[u].z;
            xacc[u * 4 + 3] += xv[u].w;
            ushort4 h;
            h.x = f2bf(xv[u].x); h.y = f2bf(xv[u].y);
            h.z = f2bf(xv[u].z); h.w = f2bf(xv[u].w);
            *(ushort4*)&xbf[r * 72 + seg * 16 + u * 4] = h;
        }
        __syncthreads();

        int inext = (i + 1 < cnt) ? (i + 1) : i;
        size_t xaddr2 = xaddr + (size_t)(inext - i) * mstride;
        float4 xv2[4];
#pragma unroll
        for (int u = 0; u < 4; ++u) xv2[u] = *(const float4*)(x + xaddr2 + u * 4);

        f32x4 acc2[4];
#pragma unroll
        for (int cf = 0; cf < 4; ++cf) acc2[cf] = zz;
#pragma unroll
        for (int ks = 0; ks < 2; ++ks) {
            bf16x8 aa = *(const bf16x8*)&xbf[(w * 16 + la) * 72 + ks * 32 + lb * 8];
#pragma unroll
            for (int cf = 0; cf < 4; ++cf) {
                bf16x8 bb = *(const bf16x8*)&WvT[(16 * cf + la) * 72 + ks * 32 + lb * 8];
                acc2[cf] = __builtin_amdgcn_mfma_f32_16x16x32_bf16(aa, bb, acc2[cf], 0, 0, 0);
            }
        }
#pragma unroll
        for (int cf = 0; cf < 4; ++cf) {
            ushort4 h;
            h.x = f2bf(acc2[cf][0] + bvv[cf]);
            h.y = f2bf(acc2[cf][1] + bvv[cf]);
            h.z = f2bf(acc2[cf][2] + bvv[cf]);
            h.w = f2bf(acc2[cf][3] + bvv[cf]);
            *(ushort4*)&vst[(16 * cf + la) * 72 + w * 16 + lb * 4] = h;
        }
        __syncthreads();

        int m = mbase + i;
        size_t vbase = ((size_t)(b * MDIM + m) * CDIM + r) * TDIM + t0 + seg * 16;
        *(uint4*)(vt + vbase) = *(const uint4*)&vst[r * 72 + seg * 16];
        *(uint4*)(vt + vbase + 8) = *(const uint4*)&vst[r * 72 + seg * 16 + 8];

#pragma unroll
        for (int u = 0; u < 4; ++u) xv[u] = xv2[u];
        xaddr = xaddr2;
    }

    size_t sbase = ((size_t)(mg * 4 + b) * TDIM + t0 + r) * CDIM + seg * 16;
#pragma unroll
    for (int u = 0; u < 4; ++u) {
        float4 o;
        o.x = xacc[u * 4 + 0]; o.y = xacc[u * 4 + 1];
        o.z = xacc[u * 4 + 2]; o.w = xacc[u * 4 + 3];
        *(float4*)(xsp + sbase + u * 4) = o;
    }
}

// ---------------------------------------------------------------- K1b: reduce 16 partials -> xsum
__global__ __launch_bounds__(256) void k_xsum2(const float* __restrict__ xsp,
                                               float* __restrict__ xsum) {
    int idx = blockIdx.x * 256 + threadIdx.x;   // 131072
    float s = 0.f;
#pragma unroll
    for (int p = 0; p < 16; ++p) s += xsp[(size_t)p * 131072 + idx];
    xsum[idx] = s;
}

// ---------------------------------------------------------------- K2: weights (qt/kt + softmax)
__global__ __launch_bounds__(256) void k_weights(const float* __restrict__ xsum,
                                                 const float* __restrict__ Wq,
                                                 const float* __restrict__ bq,
                                                 const float* __restrict__ Wk,
                                                 const float* __restrict__ bk,
                                                 ushort_t* __restrict__ wbf,
                                                 float* __restrict__ a_out) {
    __shared__ __align__(16) float kt[512][20];
    __shared__ __align__(16) float qt[32][20];
    __shared__ __align__(16) float xs[64][68];
    __shared__ __align__(16) float wcol[64][16];
    __shared__ float kbias[16], qbias[16];

    int tid = threadIdx.x;
    int bid = blockIdx.x;        // 256 blocks
    int tcn = bid & 15;          // t-chunk (32 rows)
    int n = (bid >> 4) & 3;
    int b = bid >> 6;
    int t0 = tcn * 32;

    for (int j = tid; j < 1024; j += 256) {
        int c = j >> 4, d = j & 15;
        wcol[c][d] = Wk[c * 64 + n * 16 + d];
    }
    if (tid < 16) kbias[tid] = 190.0f * bk[n * 16 + tid];
    if (tid >= 16 && tid < 32) qbias[tid - 16] = 190.0f * bq[n * 16 + tid - 16];
    __syncthreads();

    for (int ch = 0; ch < 8; ++ch) {
        for (int j = tid; j < 4096; j += 256) {
            int t = j >> 6, c = j & 63;
            xs[t][c] = xsum[((size_t)(b * 512) + (ch * 64 + t)) * 64 + c];
        }
        __syncthreads();
#pragma unroll
        for (int o = 0; o < 4; ++o) {
            int oi = o * 256 + tid;
            int t = oi >> 4, d = oi & 15;
            float s = 0.f;
#pragma unroll
            for (int c = 0; c < 64; ++c) s += xs[t][c] * wcol[c][d];
            kt[ch * 64 + t][d] = s + kbias[d];
        }
        __syncthreads();
    }

    for (int j = tid; j < 1024; j += 256) {
        int c = j >> 4, d = j & 15;
        wcol[c][d] = Wq[c * 64 + n * 16 + d];
    }
    for (int j = tid; j < 2048; j += 256) {
        int t = j >> 6, c = j & 63;
        xs[t][c] = xsum[((size_t)(b * 512) + (t0 + t)) * 64 + c];
    }
    __syncthreads();
#pragma unroll
    for (int o = 0; o < 2; ++o) {
        int oi = o * 256 + tid;
        int t = oi >> 4, d = oi & 15;
        float s = 0.f;
#pragma unroll
        for (int c = 0; c < 64; ++c) s += xs[t][c] * wcol[c][d];
        qt[t][d] = s + qbias[d];
    }
    __syncthreads();

    const float scale = 0.01813692f;  // 1/sqrt(16*190)
    int w = tid >> 6, lane = tid & 63;
    for (int rr = 0; rr < 8; ++rr) {
        int r = w * 8 + rr;
        float qreg[16];
#pragma unroll
        for (int d = 0; d < 16; ++d) qreg[d] = qt[r][d];
        float lv[8];
#pragma unroll
        for (int i = 0; i < 8; ++i) {
            int k = lane + 64 * i;
            const float* kr = &kt[k][0];
            float s = 0.f;
#pragma unroll
            for (int d = 0; d < 16; ++d) s += qreg[d] * kr[d];
            lv[i] = s * scale;
        }
        float mx = lv[0];
#pragma unroll
        for (int i = 1; i < 8; ++i) mx = fmaxf(mx, lv[i]);
#pragma unroll
        for (int off = 32; off >= 1; off >>= 1) mx = fmaxf(mx, __shfl_xor(mx, off));
        float se = 0.f;
#pragma unroll
        for (int i = 0; i < 8; ++i) { lv[i] = __expf(lv[i] - mx); se += lv[i]; }
#pragma unroll
        for (int off = 32; off >= 1; off >>= 1) se += __shfl_xor(se, off);
        float inv = 1.0f / se;

        size_t wbase = ((size_t)((b * 4 + n) * 512 + (t0 + r))) * 512;
        size_t abase = ((size_t)(n * 512 + (t0 + r))) * 512;
#pragma unroll
        for (int i = 0; i < 8; ++i) {
            float wv = lv[i] * inv;
            wbf[wbase + lane + 64 * i] = f2bf(wv);
            if (b == 0) a_out[abase + lane + 64 * i] = wv;
        }
    }
}

// ---------------------------------------------------------------- K4: register-direct att GEMM (no LDS, no barriers in main loop)
// wave = head n. A = W_n [64t x 512k] (shared over m: tied!), B = V [512k x (8m x 16d)].
// 32x32x16 MFMA; A: row=l&31, k=(l>>5)*8+j; B: col=l&31, k=(l>>5)*8+j;
// D: col=l&31, row=(reg&3)+8*(reg>>2)+4*(l>>5).
__global__ __launch_bounds__(256, 2) void k_att(const ushort_t* __restrict__ wbf,
                                                const ushort_t* __restrict__ vt,
                                                const float* __restrict__ Wp,
                                                const float* __restrict__ bp,
                                                float* __restrict__ out) {
    __shared__ __align__(16) ushort_t attS[4 * 64 * 68];   // 34816 ushorts? no: 4*64*68 = 17408 ushorts = 34.8KB
    __shared__ __align__(16) ushort_t WpT[64 * 68];

    int tid = threadIdx.x;
    int bid0 = blockIdx.x;                    // 768 = 4b * 24mt * 8tt
    int bid = (bid0 & 7) * 96 + (bid0 >> 3);  // XCD-aware bijective swizzle
    int ttile = bid & 7;
    int mt = (bid >> 3) % 24;
    int b = bid / 192;
    int t0 = ttile * 64;

    int w = tid >> 6, lane = tid & 63;
    int l31 = lane & 31, lhi = lane >> 5;
    int n = w;   // head per wave

    // stage WpT (transposed, pad 68)
#pragma unroll
    for (int rep = 0; rep < 16; ++rep) {
        int j = rep * 256 + tid;
        int ci = j >> 6, co = j & 63;
        WpT[co * 68 + ci] = f2bf(Wp[j]);
    }

    // per-lane global offsets (ushort units, 32-bit)
    unsigned wbase[2];
#pragma unroll
    for (int q = 0; q < 2; ++q)
        wbase[q] = (unsigned)(((b * 4 + n) * 512 + t0 + q * 32 + l31) * 512 + lhi * 8);
    unsigned vbase[4];
#pragma unroll
    for (int j = 0; j < 4; ++j) {
        int col = j * 32 + l31;
        int mrel = col >> 4, d = col & 15;
        int mg = mt * 8 + mrel; if (mg > 189) mg = 189;
        vbase[j] = (unsigned)(((b * 190 + mg) * 64 + n * 16 + d) * 512 + lhi * 8);
    }

    f32x16 acc[2][4];
#pragma unroll
    for (int q = 0; q < 2; ++q)
#pragma unroll
        for (int j = 0; j < 4; ++j) acc[q][j] = (f32x16)(0.f);

    bf16x8 Ae[2][2], Be[2][4], Ao[2][2], Bo[2][4];

#define LOADC(A_, B_, KC) do {                                                    \
    int ko = (KC) * 32;                                                           \
    _Pragma("unroll")                                                             \
    for (int kk = 0; kk < 2; ++kk) {                                              \
        _Pragma("unroll")                                                         \
        for (int q = 0; q < 2; ++q)                                               \
            A_[kk][q] = *(const bf16x8*)(wbf + wbase[q] + ko + kk * 16);          \
        _Pragma("unroll")                                                         \
        for (int j = 0; j < 4; ++j)                                               \
            B_[kk][j] = *(const bf16x8*)(vt + vbase[j] + ko + kk * 16);           \
    }                                                                             \
} while (0)

#define COMPC(A_, B_) do {                                                        \
    __builtin_amdgcn_s_setprio(1);                                                \
    _Pragma("unroll")                                                             \
    for (int kk = 0; kk < 2; ++kk)                                                \
        _Pragma("unroll")                                                         \
        for (int q = 0; q < 2; ++q)                                               \
            _Pragma("unroll")                                                     \
            for (int j = 0; j < 4; ++j)                                           \
                acc[q][j] = __builtin_amdgcn_mfma_f32_32x32x16_bf16(A_[kk][q], B_[kk][j], acc[q][j], 0, 0, 0); \
    __builtin_amdgcn_s_setprio(0);                                                \
} while (0)

    LOADC(Ae, Be, 0);
    LOADC(Ao, Bo, 1);
#pragma unroll
    for (int kc = 0; kc < 16; kc += 2) {
        COMPC(Ae, Be);
        if (kc + 2 < 16) LOADC(Ae, Be, kc + 2);
        COMPC(Ao, Bo);
        if (kc + 3 < 16) LOADC(Ao, Bo, kc + 3);
    }
#undef LOADC
#undef COMPC

    // ---- epilogue: att -> LDS (bf16, two m-halves), GEMM2 with Wp
    float bpv[2];
#pragma unroll
    for (int cf = 0; cf < 2; ++cf) bpv[cf] = bp[cf * 32 + l31];

#pragma unroll
    for (int h = 0; h < 2; ++h) {
        __syncthreads();   // h=0: WpT visible-fence; h=1: protect previous GEMM2 reads
#pragma unroll
        for (int q = 0; q < 2; ++q)
#pragma unroll
            for (int jj = 0; jj < 2; ++jj) {
                f32x16 a = acc[q][h * 2 + jj];
                int mloc = jj * 2 + (l31 >> 4);
                int d = l31 & 15;
#pragma unroll
                for (int r = 0; r < 16; ++r) {
                    int t = q * 32 + (r & 3) + 8 * (r >> 2) + 4 * lhi;
                    attS[(mloc * 64 + t) * 68 + w * 16 + d] = f2bf(a[r]);
                }
            }
        __syncthreads();

        // GEMM2: wave w handles m_local = w
        f32x16 acc2[2][2];
#pragma unroll
        for (int q = 0; q < 2; ++q)
#pragma unroll
            for (int cf = 0; cf < 2; ++cf) acc2[q][cf] = (f32x16)(0.f);
#pragma unroll
        for (int kk = 0; kk < 4; ++kk) {
#pragma unroll
            for (int q = 0; q < 2; ++q) {
                bf16x8 aa = *(const bf16x8*)(attS + (w * 64 + q * 32 + l31) * 68 + kk * 16 + lhi * 8);
#pragma unroll
                for (int cf = 0; cf < 2; ++cf) {
                    bf16x8 bbf = *(const bf16x8*)(WpT + (cf * 32 + l31) * 68 + kk * 16 + lhi * 8);
                    acc2[q][cf] = __builtin_amdgcn_mfma_f32_32x32x16_bf16(aa, bbf, acc2[q][cf], 0, 0, 0);
                }
            }
        }
        int m = mt * 8 + h * 4 + w;
        if (m < 190) {
            size_t obase = ((size_t)(b * 190 + m) * 512 + t0) * 64;
#pragma unroll
            for (int q = 0; q < 2; ++q)
#pragma unroll
                for (int cf = 0; cf < 2; ++cf)
#pragma unroll
                    for (int r = 0; r < 16; ++r) {
                        int t = q * 32 + (r & 3) + 8 * (r >> 2) + 4 * lhi;
                        int c = cf * 32 + l31;
                        out[obase + (size_t)t * 64 + c] = acc2[q][cf][r] + bpv[cf];
                    }
        }
    }
}

// ----------------------------------------------------------------
extern "C" void kernel_launch(void* const* d_in, const int* in_sizes, int n_in,
                              void* d_out, int out_size, void* d_ws, size_t ws_size,
                              hipStream_t stream) {
    const float* x  = (const float*)d_in[0];
    const float* Wq = (const float*)d_in[1];
    const float* bq = (const float*)d_in[2];
    const float* Wk = (const float*)d_in[3];
    const float* bk = (const float*)d_in[4];
    const float* Wv = (const float*)d_in[5];
    const float* bv = (const float*)d_in[6];
    const float* Wp = (const float*)d_in[7];
    const float* bp = (const float*)d_in[8];

    float* out = (float*)d_out;
    float* a_out = out + (size_t)BSZ * MDIM * TDIM * CDIM;   // 24903680

    // xsum partials in the out region (8 MB), fully overwritten by k_att later.
    float* xsp = out;

    float* xsum = (float*)d_ws;                                         // 512 KB
    ushort_t* wbf = (ushort_t*)((char*)d_ws + 524288);                  // 8 MB
    ushort_t* vtb = (ushort_t*)((char*)d_ws + 524288 + 8388608);        // 47.5 MB

    k_vproj<<<512, 256, 0, stream>>>(x, Wv, bv, vtb, xsp);
    k_xsum2<<<512, 256, 0, stream>>>(xsp, xsum);
    k_weights<<<256, 256, 0, stream>>>(xsum, Wq, bq, Wk, bk, wbf, a_out);
    k_att<<<768, 256, 0, stream>>>(wbf, vtb, Wp, bp, out);
}

// Round 6
// 121.864 us; speedup vs baseline: 1.2300x; 1.2300x over previous
//
#include <hip/hip_runtime.h>

typedef unsigned short ushort_t;
typedef __bf16 bf16x8 __attribute__((ext_vector_type(8)));
typedef float f32x4 __attribute__((ext_vector_type(4)));
typedef float f32x16 __attribute__((ext_vector_type(16)));

#define DEVI __device__ __forceinline__

constexpr int BSZ = 4;     // batch
constexpr int MDIM = 190;  // axial dim
constexpr int TDIM = 512;  // seq
constexpr int CDIM = 64;   // channels

DEVI ushort_t f2bf(float f) {
    union { float f; unsigned int u; } v; v.f = f;
    unsigned int u = v.u;
    u += 0x7FFFu + ((u >> 16) & 1u);   // round-to-nearest-even
    return (ushort_t)(u >> 16);
}

// ---------------------------------------------------------------- K1: fused v-projection + xsum partials
// Writes V in MFMA-fragment order: vf[b][mblk24][n][ks32][cg4][lane64][elem8],
// where col = cg*32 + l31 = (mrel,d): mrel = cg*2 + (l31>>4), d = l31&15; k = ks*16 + lhi*8 + j.
__global__ __launch_bounds__(256, 4) void k_vproj(const float* __restrict__ x,
                                                  const float* __restrict__ Wv,
                                                  const float* __restrict__ bv,
                                                  ushort_t* __restrict__ vf,
                                                  float* __restrict__ xsp) {
    __shared__ __align__(16) ushort_t xbf[64 * 72];
    __shared__ __align__(16) ushort_t WvT[64 * 72];
    __shared__ __align__(16) ushort_t vst[64 * 72];

    int tid = threadIdx.x;
    int bid = blockIdx.x;            // 512 = 4b * 8tt * 16mg
    int mg = bid & 15;
    int tt = (bid >> 4) & 7;
    int b = bid >> 7;
    int t0 = tt * 64;
    int mbase = mg * 12;
    int cnt = (mbase + 12 <= MDIM) ? 12 : (MDIM - mbase);   // 12 or 10

    int w = tid >> 6, lane = tid & 63;
    int la = lane & 15, lb = lane >> 4;
    int r = tid >> 2, seg = tid & 3;

    // frag-write decomposition (per m): chunk = tid>>3 -> (ksr, n, lhi); u = tid&7 -> d pair
    int chunk = tid >> 3, u = tid & 7;
    int ksr = chunk >> 3;
    int nn2 = (chunk >> 1) & 3;
    int lhi2 = chunk & 1;
    int d0 = u * 2;

#pragma unroll
    for (int rep = 0; rep < 16; ++rep) {
        int j = rep * 256 + tid;
        int ci = j >> 6, co = j & 63;
        WvT[co * 72 + ci] = f2bf(Wv[j]);
    }
    float bvv[4];
#pragma unroll
    for (int cf = 0; cf < 4; ++cf) bvv[cf] = bv[16 * cf + la];

    float xacc[16];
#pragma unroll
    for (int u2 = 0; u2 < 16; ++u2) xacc[u2] = 0.f;

    const size_t mstride = (size_t)TDIM * CDIM;  // 32768
    size_t xaddr = ((size_t)(b * MDIM + mbase) * TDIM + t0 + r) * CDIM + seg * 16;

    float4 xv[4];
#pragma unroll
    for (int u2 = 0; u2 < 4; ++u2) xv[u2] = *(const float4*)(x + xaddr + u2 * 4);

    f32x4 zz = {0.f, 0.f, 0.f, 0.f};

    for (int i = 0; i < cnt; ++i) {
#pragma unroll
        for (int u2 = 0; u2 < 4; ++u2) {
            xacc[u2 * 4 + 0] += xv[u2].x;
            xacc[u2 * 4 + 1] += xv[u2].y;
            xacc[u2 * 4 + 2] += xv[u2].z;
            xacc[u2 * 4 + 3] += xv[u2].w;
            ushort4 h;
            h.x = f2bf(xv[u2].x); h.y = f2bf(xv[u2].y);
            h.z = f2bf(xv[u2].z); h.w = f2bf(xv[u2].w);
            *(ushort4*)&xbf[r * 72 + seg * 16 + u2 * 4] = h;
        }
        __syncthreads();

        int inext = (i + 1 < cnt) ? (i + 1) : i;
        size_t xaddr2 = xaddr + (size_t)(inext - i) * mstride;
        float4 xv2[4];
#pragma unroll
        for (int u2 = 0; u2 < 4; ++u2) xv2[u2] = *(const float4*)(x + xaddr2 + u2 * 4);

        f32x4 acc2[4];
#pragma unroll
        for (int cf = 0; cf < 4; ++cf) acc2[cf] = zz;
#pragma unroll
        for (int ks = 0; ks < 2; ++ks) {
            bf16x8 aa = *(const bf16x8*)&xbf[(w * 16 + la) * 72 + ks * 32 + lb * 8];
#pragma unroll
            for (int cf = 0; cf < 4; ++cf) {
                bf16x8 bb = *(const bf16x8*)&WvT[(16 * cf + la) * 72 + ks * 32 + lb * 8];
                acc2[cf] = __builtin_amdgcn_mfma_f32_16x16x32_bf16(aa, bb, acc2[cf], 0, 0, 0);
            }
        }
#pragma unroll
        for (int cf = 0; cf < 4; ++cf) {
            ushort4 h;
            h.x = f2bf(acc2[cf][0] + bvv[cf]);
            h.y = f2bf(acc2[cf][1] + bvv[cf]);
            h.z = f2bf(acc2[cf][2] + bvv[cf]);
            h.w = f2bf(acc2[cf][3] + bvv[cf]);
            *(ushort4*)&vst[(16 * cf + la) * 72 + w * 16 + lb * 4] = h;   // vst[c][t_rel]
        }
        __syncthreads();

        // frag-order global write (32B/thread, 256B contiguous per 8-thread chunk)
        int m = mbase + i;
        int mblk = m >> 3, mrel = m & 7;
        size_t vfbase = ((size_t)((((b * 24 + mblk) * 4 + nn2) * 32) + tt * 4 + ksr) * 4 + (mrel >> 1)) * 512
                      + (size_t)(lhi2 * 32 + (mrel & 1) * 16 + d0) * 8;
        uint4 v0 = *(const uint4*)&vst[(nn2 * 16 + d0) * 72 + ksr * 16 + lhi2 * 8];
        uint4 v1 = *(const uint4*)&vst[(nn2 * 16 + d0 + 1) * 72 + ksr * 16 + lhi2 * 8];
        *(uint4*)(vf + vfbase) = v0;
        *(uint4*)(vf + vfbase + 8) = v1;

#pragma unroll
        for (int u2 = 0; u2 < 4; ++u2) xv[u2] = xv2[u2];
        xaddr = xaddr2;
    }

    // zero-fill phantom m = 190,191 (mblk 23, mrel 6,7)
    if (mg == 15) {
        uint4 z4 = {0u, 0u, 0u, 0u};
#pragma unroll
        for (int pm = 190; pm < 192; ++pm) {
            int mblk = pm >> 3, mrel = pm & 7;
            size_t vfbase = ((size_t)((((b * 24 + mblk) * 4 + nn2) * 32) + tt * 4 + ksr) * 4 + (mrel >> 1)) * 512
                          + (size_t)(lhi2 * 32 + (mrel & 1) * 16 + d0) * 8;
            *(uint4*)(vf + vfbase) = z4;
            *(uint4*)(vf + vfbase + 8) = z4;
        }
    }

    size_t sbase = ((size_t)(mg * 4 + b) * TDIM + t0 + r) * CDIM + seg * 16;
#pragma unroll
    for (int u2 = 0; u2 < 4; ++u2) {
        float4 o;
        o.x = xacc[u2 * 4 + 0]; o.y = xacc[u2 * 4 + 1];
        o.z = xacc[u2 * 4 + 2]; o.w = xacc[u2 * 4 + 3];
        *(float4*)(xsp + sbase + u2 * 4) = o;
    }
}

// ---------------------------------------------------------------- K1b: reduce 16 partials -> xsum
__global__ __launch_bounds__(256) void k_xsum2(const float* __restrict__ xsp,
                                               float* __restrict__ xsum) {
    int idx = blockIdx.x * 256 + threadIdx.x;   // 131072
    float s = 0.f;
#pragma unroll
    for (int p = 0; p < 16; ++p) s += xsp[(size_t)p * 131072 + idx];
    xsum[idx] = s;
}

// ---------------------------------------------------------------- K2: weights (qt/kt + softmax), frag-order output
// wf[b][n][tq16][ks32][lane64][elem8]: row = tq*32 + l31, k = ks*16 + lhi*8 + j.
__global__ __launch_bounds__(256) void k_weights(const float* __restrict__ xsum,
                                                 const float* __restrict__ Wq,
                                                 const float* __restrict__ bq,
                                                 const float* __restrict__ Wk,
                                                 const float* __restrict__ bk,
                                                 ushort_t* __restrict__ wf,
                                                 float* __restrict__ a_out) {
    __shared__ __align__(16) float kt[512][20];
    __shared__ __align__(16) float qt[32][20];
    __shared__ __align__(16) float xs[64][68];
    __shared__ __align__(16) float wcol[64][16];
    __shared__ float kbias[16], qbias[16];
    __shared__ __align__(16) ushort_t rowbuf[32][520];

    int tid = threadIdx.x;
    int bid = blockIdx.x;        // 256 blocks
    int tcn = bid & 15;          // t-chunk (32 rows) == tq
    int n = (bid >> 4) & 3;
    int b = bid >> 6;
    int t0 = tcn * 32;

    for (int j = tid; j < 1024; j += 256) {
        int c = j >> 4, d = j & 15;
        wcol[c][d] = Wk[c * 64 + n * 16 + d];
    }
    if (tid < 16) kbias[tid] = 190.0f * bk[n * 16 + tid];
    if (tid >= 16 && tid < 32) qbias[tid - 16] = 190.0f * bq[n * 16 + tid - 16];
    __syncthreads();

    for (int ch = 0; ch < 8; ++ch) {
        for (int j = tid; j < 4096; j += 256) {
            int t = j >> 6, c = j & 63;
            xs[t][c] = xsum[((size_t)(b * 512) + (ch * 64 + t)) * 64 + c];
        }
        __syncthreads();
#pragma unroll
        for (int o = 0; o < 4; ++o) {
            int oi = o * 256 + tid;
            int t = oi >> 4, d = oi & 15;
            float s = 0.f;
#pragma unroll
            for (int c = 0; c < 64; ++c) s += xs[t][c] * wcol[c][d];
            kt[ch * 64 + t][d] = s + kbias[d];
        }
        __syncthreads();
    }

    for (int j = tid; j < 1024; j += 256) {
        int c = j >> 4, d = j & 15;
        wcol[c][d] = Wq[c * 64 + n * 16 + d];
    }
    for (int j = tid; j < 2048; j += 256) {
        int t = j >> 6, c = j & 63;
        xs[t][c] = xsum[((size_t)(b * 512) + (t0 + t)) * 64 + c];
    }
    __syncthreads();
#pragma unroll
    for (int o = 0; o < 2; ++o) {
        int oi = o * 256 + tid;
        int t = oi >> 4, d = oi & 15;
        float s = 0.f;
#pragma unroll
        for (int c = 0; c < 64; ++c) s += xs[t][c] * wcol[c][d];
        qt[t][d] = s + qbias[d];
    }
    __syncthreads();

    const float scale = 0.01813692f;  // 1/sqrt(16*190)
    int w = tid >> 6, lane = tid & 63;
    for (int rr = 0; rr < 8; ++rr) {
        int r = w * 8 + rr;
        float qreg[16];
#pragma unroll
        for (int d = 0; d < 16; ++d) qreg[d] = qt[r][d];
        float lv[8];
#pragma unroll
        for (int i = 0; i < 8; ++i) {
            int k = lane + 64 * i;
            const float* kr = &kt[k][0];
            float s = 0.f;
#pragma unroll
            for (int d = 0; d < 16; ++d) s += qreg[d] * kr[d];
            lv[i] = s * scale;
        }
        float mx = lv[0];
#pragma unroll
        for (int i = 1; i < 8; ++i) mx = fmaxf(mx, lv[i]);
#pragma unroll
        for (int off = 32; off >= 1; off >>= 1) mx = fmaxf(mx, __shfl_xor(mx, off));
        float se = 0.f;
#pragma unroll
        for (int i = 0; i < 8; ++i) { lv[i] = __expf(lv[i] - mx); se += lv[i]; }
#pragma unroll
        for (int off = 32; off >= 1; off >>= 1) se += __shfl_xor(se, off);
        float inv = 1.0f / se;

        size_t abase = ((size_t)(n * 512 + (t0 + r))) * 512;
#pragma unroll
        for (int i = 0; i < 8; ++i) {
            float wv = lv[i] * inv;
            rowbuf[r][lane + 64 * i] = f2bf(wv);
            if (b == 0) a_out[abase + lane + 64 * i] = wv;
        }
    }
    __syncthreads();

    // frag-order write-out: 8 passes x 256 threads x 16B
    size_t wfbase = ((size_t)((b * 4 + n) * 16 + tcn)) * 32 * 512;
#pragma unroll
    for (int p = 0; p < 8; ++p) {
        int id = p * 256 + tid;          // 0..2047
        int ks = id >> 6;
        int lf = id & 63;
        int l31 = lf & 31, lhi = lf >> 5;
        uint4 v = *(const uint4*)&rowbuf[l31][ks * 16 + lhi * 8];
        *(uint4*)(wf + wfbase + (size_t)ks * 512 + lf * 8) = v;
    }
}

// ---------------------------------------------------------------- K4: register-direct att GEMM, frag-order coalesced loads
__global__ __launch_bounds__(256, 2) void k_att(const ushort_t* __restrict__ wf,
                                                const ushort_t* __restrict__ vf,
                                                const float* __restrict__ Wp,
                                                const float* __restrict__ bp,
                                                float* __restrict__ out) {
    __shared__ __align__(16) ushort_t attS[4 * 64 * 68];
    __shared__ __align__(16) ushort_t WpT[64 * 68];

    int tid = threadIdx.x;
    int bid0 = blockIdx.x;                    // 768 = 4b * 24mt * 8tt
    int bid = (bid0 & 7) * 96 + (bid0 >> 3);  // XCD-aware bijective swizzle
    int ttile = bid & 7;
    int mt = (bid >> 3) % 24;                 // mblk
    int b = bid / 192;

    int w = tid >> 6, lane = tid & 63;
    int l31 = lane & 31, lhi = lane >> 5;
    int n = w;   // head per wave

#pragma unroll
    for (int rep = 0; rep < 16; ++rep) {
        int j = rep * 256 + tid;
        int ci = j >> 6, co = j & 63;
        WpT[co * 68 + ci] = f2bf(Wp[j]);
    }

    // coalesced frag bases (all loads = base + ks*step + lane*8)
    unsigned abase[2];
#pragma unroll
    for (int q = 0; q < 2; ++q)
        abase[q] = (unsigned)((((b * 4 + n) * 16 + ttile * 2 + q) * 32) * 512 + lane * 8);
    unsigned bbase[4];
#pragma unroll
    for (int j = 0; j < 4; ++j)
        bbase[j] = (unsigned)(((((b * 24 + mt) * 4 + n) * 32) * 4 + j) * 512 + lane * 8);

    f32x16 acc[2][4];
#pragma unroll
    for (int q = 0; q < 2; ++q)
#pragma unroll
        for (int j = 0; j < 4; ++j) acc[q][j] = (f32x16)(0.f);

    bf16x8 Ae[2][2], Be[2][4], Ao[2][2], Bo[2][4];

#define LOADC(A_, B_, KC) do {                                                    \
    _Pragma("unroll")                                                             \
    for (int kk = 0; kk < 2; ++kk) {                                              \
        int ks = (KC) * 2 + kk;                                                   \
        _Pragma("unroll")                                                         \
        for (int q = 0; q < 2; ++q)                                               \
            A_[kk][q] = *(const bf16x8*)(wf + abase[q] + ks * 512);               \
        _Pragma("unroll")                                                         \
        for (int j = 0; j < 4; ++j)                                               \
            B_[kk][j] = *(const bf16x8*)(vf + bbase[j] + ks * 2048);              \
    }                                                                             \
} while (0)

#define COMPC(A_, B_) do {                                                        \
    __builtin_amdgcn_s_setprio(1);                                                \
    _Pragma("unroll")                                                             \
    for (int kk = 0; kk < 2; ++kk)                                                \
        _Pragma("unroll")                                                         \
        for (int q = 0; q < 2; ++q)                                               \
            _Pragma("unroll")                                                     \
            for (int j = 0; j < 4; ++j)                                           \
                acc[q][j] = __builtin_amdgcn_mfma_f32_32x32x16_bf16(A_[kk][q], B_[kk][j], acc[q][j], 0, 0, 0); \
    __builtin_amdgcn_s_setprio(0);                                                \
} while (0)

    LOADC(Ae, Be, 0);
    LOADC(Ao, Bo, 1);
#pragma unroll
    for (int kc = 0; kc < 16; kc += 2) {
        COMPC(Ae, Be);
        if (kc + 2 < 16) LOADC(Ae, Be, kc + 2);
        COMPC(Ao, Bo);
        if (kc + 3 < 16) LOADC(Ao, Bo, kc + 3);
    }
#undef LOADC
#undef COMPC

    // ---- epilogue: att -> LDS (bf16, two m-halves), GEMM2 with Wp
    float bpv[2];
#pragma unroll
    for (int cf = 0; cf < 2; ++cf) bpv[cf] = bp[cf * 32 + l31];

#pragma unroll
    for (int h = 0; h < 2; ++h) {
        __syncthreads();
#pragma unroll
        for (int q = 0; q < 2; ++q)
#pragma unroll
            for (int jj = 0; jj < 2; ++jj) {
                f32x16 a = acc[q][h * 2 + jj];
                int mloc = jj * 2 + (l31 >> 4);
                int d = l31 & 15;
#pragma unroll
                for (int r = 0; r < 16; ++r) {
                    int t = q * 32 + (r & 3) + 8 * (r >> 2) + 4 * lhi;
                    attS[(mloc * 64 + t) * 68 + w * 16 + d] = f2bf(a[r]);
                }
            }
        __syncthreads();

        f32x16 acc2[2][2];
#pragma unroll
        for (int q = 0; q < 2; ++q)
#pragma unroll
            for (int cf = 0; cf < 2; ++cf) acc2[q][cf] = (f32x16)(0.f);
#pragma unroll
        for (int kk = 0; kk < 4; ++kk) {
#pragma unroll
            for (int q = 0; q < 2; ++q) {
                bf16x8 aa = *(const bf16x8*)(attS + (w * 64 + q * 32 + l31) * 68 + kk * 16 + lhi * 8);
#pragma unroll
                for (int cf = 0; cf < 2; ++cf) {
                    bf16x8 bbf = *(const bf16x8*)(WpT + (cf * 32 + l31) * 68 + kk * 16 + lhi * 8);
                    acc2[q][cf] = __builtin_amdgcn_mfma_f32_32x32x16_bf16(aa, bbf, acc2[q][cf], 0, 0, 0);
                }
            }
        }
        int m = mt * 8 + h * 4 + w;
        if (m < 190) {
            size_t obase = ((size_t)(b * 190 + m) * 512 + ttile * 64) * 64;
#pragma unroll
            for (int q = 0; q < 2; ++q)
#pragma unroll
                for (int cf = 0; cf < 2; ++cf)
#pragma unroll
                    for (int r = 0; r < 16; ++r) {
                        int t = q * 32 + (r & 3) + 8 * (r >> 2) + 4 * lhi;
                        int c = cf * 32 + l31;
                        out[obase + (size_t)t * 64 + c] = acc2[q][cf][r] + bpv[cf];
                    }
        }
    }
}

// ----------------------------------------------------------------
extern "C" void kernel_launch(void* const* d_in, const int* in_sizes, int n_in,
                              void* d_out, int out_size, void* d_ws, size_t ws_size,
                              hipStream_t stream) {
    const float* x  = (const float*)d_in[0];
    const float* Wq = (const float*)d_in[1];
    const float* bq = (const float*)d_in[2];
    const float* Wk = (const float*)d_in[3];
    const float* bk = (const float*)d_in[4];
    const float* Wv = (const float*)d_in[5];
    const float* bv = (const float*)d_in[6];
    const float* Wp = (const float*)d_in[7];
    const float* bp = (const float*)d_in[8];

    float* out = (float*)d_out;
    float* a_out = out + (size_t)BSZ * MDIM * TDIM * CDIM;   // 24903680

    // xsum partials in the out region (8 MB), fully overwritten by k_att later.
    float* xsp = out;

    float* xsum = (float*)d_ws;                                         // 512 KB
    ushort_t* wf = (ushort_t*)((char*)d_ws + 524288);                   // 8.39 MB (4*4*16*32*512)
    ushort_t* vf = (ushort_t*)((char*)d_ws + 524288 + 8388608);         // 50.33 MB (4*24*4*32*4*512)

    k_vproj<<<512, 256, 0, stream>>>(x, Wv, bv, vf, xsp);
    k_xsum2<<<512, 256, 0, stream>>>(xsp, xsum);
    k_weights<<<256, 256, 0, stream>>>(xsum, Wq, bq, Wk, bk, wf, a_out);
    k_att<<<768, 256, 0, stream>>>(wf, vf, Wp, bp, out);
}

// Round 7
// 117.975 us; speedup vs baseline: 1.2705x; 1.0330x over previous
//
#include <hip/hip_runtime.h>

typedef unsigned short ushort_t;
typedef __bf16 bf16x8 __attribute__((ext_vector_type(8)));
typedef float f32x4 __attribute__((ext_vector_type(4)));
typedef float f32x16 __attribute__((ext_vector_type(16)));

#define DEVI __device__ __forceinline__

constexpr int BSZ = 4;     // batch
constexpr int MDIM = 190;  // axial dim
constexpr int TDIM = 512;  // seq
constexpr int CDIM = 64;   // channels

DEVI ushort_t f2bf(float f) {
    union { float f; unsigned int u; } v; v.f = f;
    unsigned int u = v.u;
    u += 0x7FFFu + ((u >> 16) & 1u);   // round-to-nearest-even
    return (ushort_t)(u >> 16);
}

// ---------------------------------------------------------------- K1: fused v-projection + xsum partials
// Writes V in MFMA-fragment order: vf[b][mblk24][n][ks32][cg4][lane64][elem8],
// where col = cg*32 + l31 = (mrel,d): mrel = cg*2 + (l31>>4), d = l31&15; k = ks*16 + lhi*8 + j.
__global__ __launch_bounds__(256, 4) void k_vproj(const float* __restrict__ x,
                                                  const float* __restrict__ Wv,
                                                  const float* __restrict__ bv,
                                                  ushort_t* __restrict__ vf,
                                                  float* __restrict__ xsp) {
    __shared__ __align__(16) ushort_t xbf[64 * 72];
    __shared__ __align__(16) ushort_t WvT[64 * 72];
    __shared__ __align__(16) ushort_t vst[64 * 72];

    int tid = threadIdx.x;
    int bid = blockIdx.x;            // 512 = 4b * 8tt * 16mg
    int mg = bid & 15;
    int tt = (bid >> 4) & 7;
    int b = bid >> 7;
    int t0 = tt * 64;
    int mbase = mg * 12;
    int cnt = (mbase + 12 <= MDIM) ? 12 : (MDIM - mbase);   // 12 or 10

    int w = tid >> 6, lane = tid & 63;
    int la = lane & 15, lb = lane >> 4;
    int r = tid >> 2, seg = tid & 3;

    // frag-write decomposition (per m): chunk = tid>>3 -> (ksr, n, lhi); u = tid&7 -> d pair
    int chunk = tid >> 3, u = tid & 7;
    int ksr = chunk >> 3;
    int nn2 = (chunk >> 1) & 3;
    int lhi2 = chunk & 1;
    int d0 = u * 2;

#pragma unroll
    for (int rep = 0; rep < 16; ++rep) {
        int j = rep * 256 + tid;
        int ci = j >> 6, co = j & 63;
        WvT[co * 72 + ci] = f2bf(Wv[j]);
    }
    float bvv[4];
#pragma unroll
    for (int cf = 0; cf < 4; ++cf) bvv[cf] = bv[16 * cf + la];

    float xacc[16];
#pragma unroll
    for (int u2 = 0; u2 < 16; ++u2) xacc[u2] = 0.f;

    const size_t mstride = (size_t)TDIM * CDIM;  // 32768
    size_t xaddr = ((size_t)(b * MDIM + mbase) * TDIM + t0 + r) * CDIM + seg * 16;

    float4 xv[4];
#pragma unroll
    for (int u2 = 0; u2 < 4; ++u2) xv[u2] = *(const float4*)(x + xaddr + u2 * 4);

    f32x4 zz = {0.f, 0.f, 0.f, 0.f};

    for (int i = 0; i < cnt; ++i) {
#pragma unroll
        for (int u2 = 0; u2 < 4; ++u2) {
            xacc[u2 * 4 + 0] += xv[u2].x;
            xacc[u2 * 4 + 1] += xv[u2].y;
            xacc[u2 * 4 + 2] += xv[u2].z;
            xacc[u2 * 4 + 3] += xv[u2].w;
            ushort4 h;
            h.x = f2bf(xv[u2].x); h.y = f2bf(xv[u2].y);
            h.z = f2bf(xv[u2].z); h.w = f2bf(xv[u2].w);
            *(ushort4*)&xbf[r * 72 + seg * 16 + u2 * 4] = h;
        }
        __syncthreads();

        int inext = (i + 1 < cnt) ? (i + 1) : i;
        size_t xaddr2 = xaddr + (size_t)(inext - i) * mstride;
        float4 xv2[4];
#pragma unroll
        for (int u2 = 0; u2 < 4; ++u2) xv2[u2] = *(const float4*)(x + xaddr2 + u2 * 4);

        f32x4 acc2[4];
#pragma unroll
        for (int cf = 0; cf < 4; ++cf) acc2[cf] = zz;
#pragma unroll
        for (int ks = 0; ks < 2; ++ks) {
            bf16x8 aa = *(const bf16x8*)&xbf[(w * 16 + la) * 72 + ks * 32 + lb * 8];
#pragma unroll
            for (int cf = 0; cf < 4; ++cf) {
                bf16x8 bb = *(const bf16x8*)&WvT[(16 * cf + la) * 72 + ks * 32 + lb * 8];
                acc2[cf] = __builtin_amdgcn_mfma_f32_16x16x32_bf16(aa, bb, acc2[cf], 0, 0, 0);
            }
        }
#pragma unroll
        for (int cf = 0; cf < 4; ++cf) {
            ushort4 h;
            h.x = f2bf(acc2[cf][0] + bvv[cf]);
            h.y = f2bf(acc2[cf][1] + bvv[cf]);
            h.z = f2bf(acc2[cf][2] + bvv[cf]);
            h.w = f2bf(acc2[cf][3] + bvv[cf]);
            *(ushort4*)&vst[(16 * cf + la) * 72 + w * 16 + lb * 4] = h;   // vst[c][t_rel]
        }
        __syncthreads();

        // frag-order global write (32B/thread, 256B contiguous per 8-thread chunk)
        int m = mbase + i;
        int mblk = m >> 3, mrel = m & 7;
        size_t vfbase = ((size_t)((((b * 24 + mblk) * 4 + nn2) * 32) + tt * 4 + ksr) * 4 + (mrel >> 1)) * 512
                      + (size_t)(lhi2 * 32 + (mrel & 1) * 16 + d0) * 8;
        uint4 v0 = *(const uint4*)&vst[(nn2 * 16 + d0) * 72 + ksr * 16 + lhi2 * 8];
        uint4 v1 = *(const uint4*)&vst[(nn2 * 16 + d0 + 1) * 72 + ksr * 16 + lhi2 * 8];
        *(uint4*)(vf + vfbase) = v0;
        *(uint4*)(vf + vfbase + 8) = v1;

#pragma unroll
        for (int u2 = 0; u2 < 4; ++u2) xv[u2] = xv2[u2];
        xaddr = xaddr2;
    }

    // zero-fill phantom m = 190,191 (mblk 23, mrel 6,7)
    if (mg == 15) {
        uint4 z4 = {0u, 0u, 0u, 0u};
#pragma unroll
        for (int pm = 190; pm < 192; ++pm) {
            int mblk = pm >> 3, mrel = pm & 7;
            size_t vfbase = ((size_t)((((b * 24 + mblk) * 4 + nn2) * 32) + tt * 4 + ksr) * 4 + (mrel >> 1)) * 512
                          + (size_t)(lhi2 * 32 + (mrel & 1) * 16 + d0) * 8;
            *(uint4*)(vf + vfbase) = z4;
            *(uint4*)(vf + vfbase + 8) = z4;
        }
    }

    size_t sbase = ((size_t)(mg * 4 + b) * TDIM + t0 + r) * CDIM + seg * 16;
#pragma unroll
    for (int u2 = 0; u2 < 4; ++u2) {
        float4 o;
        o.x = xacc[u2 * 4 + 0]; o.y = xacc[u2 * 4 + 1];
        o.z = xacc[u2 * 4 + 2]; o.w = xacc[u2 * 4 + 3];
        *(float4*)(xsp + sbase + u2 * 4) = o;
    }
}

// ---------------------------------------------------------------- K1b: reduce 16 partials -> xsum
__global__ __launch_bounds__(256) void k_xsum2(const float* __restrict__ xsp,
                                               float* __restrict__ xsum) {
    int idx = blockIdx.x * 256 + threadIdx.x;   // 131072
    float s = 0.f;
#pragma unroll
    for (int p = 0; p < 16; ++p) s += xsp[(size_t)p * 131072 + idx];
    xsum[idx] = s;
}

// ---------------------------------------------------------------- K2: weights (qt/kt + softmax), frag-order output
// wf[b][n][tq16][ks32][lane64][elem8]: row = tq*32 + l31, k = ks*16 + lhi*8 + j.
__global__ __launch_bounds__(256) void k_weights(const float* __restrict__ xsum,
                                                 const float* __restrict__ Wq,
                                                 const float* __restrict__ bq,
                                                 const float* __restrict__ Wk,
                                                 const float* __restrict__ bk,
                                                 ushort_t* __restrict__ wf,
                                                 float* __restrict__ a_out) {
    __shared__ __align__(16) float kt[512][20];
    __shared__ __align__(16) float qt[32][20];
    __shared__ __align__(16) float xs[64][68];
    __shared__ __align__(16) float wcol[64][16];
    __shared__ float kbias[16], qbias[16];
    __shared__ __align__(16) ushort_t rowbuf[32][520];

    int tid = threadIdx.x;
    int bid = blockIdx.x;        // 256 blocks
    int tcn = bid & 15;          // t-chunk (32 rows) == tq
    int n = (bid >> 4) & 3;
    int b = bid >> 6;
    int t0 = tcn * 32;

    for (int j = tid; j < 1024; j += 256) {
        int c = j >> 4, d = j & 15;
        wcol[c][d] = Wk[c * 64 + n * 16 + d];
    }
    if (tid < 16) kbias[tid] = 190.0f * bk[n * 16 + tid];
    if (tid >= 16 && tid < 32) qbias[tid - 16] = 190.0f * bq[n * 16 + tid - 16];
    __syncthreads();

    for (int ch = 0; ch < 8; ++ch) {
        for (int j = tid; j < 4096; j += 256) {
            int t = j >> 6, c = j & 63;
            xs[t][c] = xsum[((size_t)(b * 512) + (ch * 64 + t)) * 64 + c];
        }
        __syncthreads();
#pragma unroll
        for (int o = 0; o < 4; ++o) {
            int oi = o * 256 + tid;
            int t = oi >> 4, d = oi & 15;
            float s = 0.f;
#pragma unroll
            for (int c = 0; c < 64; ++c) s += xs[t][c] * wcol[c][d];
            kt[ch * 64 + t][d] = s + kbias[d];
        }
        __syncthreads();
    }

    for (int j = tid; j < 1024; j += 256) {
        int c = j >> 4, d = j & 15;
        wcol[c][d] = Wq[c * 64 + n * 16 + d];
    }
    for (int j = tid; j < 2048; j += 256) {
        int t = j >> 6, c = j & 63;
        xs[t][c] = xsum[((size_t)(b * 512) + (t0 + t)) * 64 + c];
    }
    __syncthreads();
#pragma unroll
    for (int o = 0; o < 2; ++o) {
        int oi = o * 256 + tid;
        int t = oi >> 4, d = oi & 15;
        float s = 0.f;
#pragma unroll
        for (int c = 0; c < 64; ++c) s += xs[t][c] * wcol[c][d];
        qt[t][d] = s + qbias[d];
    }
    __syncthreads();

    const float scale = 0.01813692f;  // 1/sqrt(16*190)
    int w = tid >> 6, lane = tid & 63;
    for (int rr = 0; rr < 8; ++rr) {
        int r = w * 8 + rr;
        float qreg[16];
#pragma unroll
        for (int d = 0; d < 16; ++d) qreg[d] = qt[r][d];
        float lv[8];
#pragma unroll
        for (int i = 0; i < 8; ++i) {
            int k = lane + 64 * i;
            const float* kr = &kt[k][0];
            float s = 0.f;
#pragma unroll
            for (int d = 0; d < 16; ++d) s += qreg[d] * kr[d];
            lv[i] = s * scale;
        }
        float mx = lv[0];
#pragma unroll
        for (int i = 1; i < 8; ++i) mx = fmaxf(mx, lv[i]);
#pragma unroll
        for (int off = 32; off >= 1; off >>= 1) mx = fmaxf(mx, __shfl_xor(mx, off));
        float se = 0.f;
#pragma unroll
        for (int i = 0; i < 8; ++i) { lv[i] = __expf(lv[i] - mx); se += lv[i]; }
#pragma unroll
        for (int off = 32; off >= 1; off >>= 1) se += __shfl_xor(se, off);
        float inv = 1.0f / se;

        size_t abase = ((size_t)(n * 512 + (t0 + r))) * 512;
#pragma unroll
        for (int i = 0; i < 8; ++i) {
            float wv = lv[i] * inv;
            rowbuf[r][lane + 64 * i] = f2bf(wv);
            if (b == 0) a_out[abase + lane + 64 * i] = wv;
        }
    }
    __syncthreads();

    // frag-order write-out: 8 passes x 256 threads x 16B
    size_t wfbase = ((size_t)((b * 4 + n) * 16 + tcn)) * 32 * 512;
#pragma unroll
    for (int p = 0; p < 8; ++p) {
        int id = p * 256 + tid;          // 0..2047
        int ks = id >> 6;
        int lf = id & 63;
        int l31 = lf & 31, lhi = lf >> 5;
        uint4 v = *(const uint4*)&rowbuf[l31][ks * 16 + lhi * 8];
        *(uint4*)(wf + wfbase + (size_t)ks * 512 + lf * 8) = v;
    }
}

// ---------------------------------------------------------------- K4: register-direct att GEMM, counted-vmcnt pipeline
__global__ __launch_bounds__(256, 2) void k_att(const ushort_t* __restrict__ wf,
                                                const ushort_t* __restrict__ vf,
                                                const float* __restrict__ Wp,
                                                const float* __restrict__ bp,
                                                float* __restrict__ out) {
    __shared__ __align__(16) ushort_t attS[4 * 64 * 68];
    __shared__ __align__(16) ushort_t WpT[64 * 68];

    int tid = threadIdx.x;
    int bid0 = blockIdx.x;                    // 768 = 4b * 24mt * 8tt
    int bid = (bid0 & 7) * 96 + (bid0 >> 3);  // XCD-aware bijective swizzle
    int ttile = bid & 7;
    int mt = (bid >> 3) % 24;                 // mblk
    int b = bid / 192;

    int w = tid >> 6, lane = tid & 63;
    int l31 = lane & 31, lhi = lane >> 5;
    int n = w;   // head per wave

#pragma unroll
    for (int rep = 0; rep < 16; ++rep) {
        int j = rep * 256 + tid;
        int ci = j >> 6, co = j & 63;
        WpT[co * 68 + ci] = f2bf(Wp[j]);
    }

    // coalesced frag bases (all loads = base + ks*step + lane*8)
    unsigned abase[2];
#pragma unroll
    for (int q = 0; q < 2; ++q)
        abase[q] = (unsigned)((((b * 4 + n) * 16 + ttile * 2 + q) * 32) * 512 + lane * 8);
    unsigned bbase[4];
#pragma unroll
    for (int j = 0; j < 4; ++j)
        bbase[j] = (unsigned)(((((b * 24 + mt) * 4 + n) * 32) * 4 + j) * 512 + lane * 8);

    f32x16 acc[2][4];
#pragma unroll
    for (int q = 0; q < 2; ++q)
#pragma unroll
        for (int j = 0; j < 4; ++j) acc[q][j] = (f32x16)(0.f);

    bf16x8 Ae[2][2], Be[2][4], Ao[2][2], Bo[2][4];

#define LOADC(A_, B_, KC) do {                                                    \
    _Pragma("unroll")                                                             \
    for (int kk = 0; kk < 2; ++kk) {                                              \
        int ks = (KC) * 2 + kk;                                                   \
        _Pragma("unroll")                                                         \
        for (int q = 0; q < 2; ++q)                                               \
            A_[kk][q] = *(const bf16x8*)(wf + abase[q] + ks * 512);               \
        _Pragma("unroll")                                                         \
        for (int j = 0; j < 4; ++j)                                               \
            B_[kk][j] = *(const bf16x8*)(vf + bbase[j] + ks * 2048);              \
    }                                                                             \
} while (0)

#define COMPC(A_, B_) do {                                                        \
    _Pragma("unroll")                                                             \
    for (int kk = 0; kk < 2; ++kk)                                                \
        _Pragma("unroll")                                                         \
        for (int q = 0; q < 2; ++q)                                               \
            _Pragma("unroll")                                                     \
            for (int j = 0; j < 4; ++j)                                           \
                acc[q][j] = __builtin_amdgcn_mfma_f32_32x32x16_bf16(A_[kk][q], B_[kk][j], acc[q][j], 0, 0, 0); \
} while (0)

#define VM12 do { asm volatile("s_waitcnt vmcnt(12)" ::: "memory"); __builtin_amdgcn_sched_barrier(0); } while (0)
#define VM0  do { asm volatile("s_waitcnt vmcnt(0)"  ::: "memory"); __builtin_amdgcn_sched_barrier(0); } while (0)

    LOADC(Ae, Be, 0);
    LOADC(Ao, Bo, 1);
#pragma unroll
    for (int kc = 0; kc < 14; kc += 2) {
        VM12;                       // set-E(kc) landed; set-O(kc+1)'s 12 stay in flight
        COMPC(Ae, Be);
        LOADC(Ae, Be, kc + 2);      // 24 in flight
        VM12;                       // set-O(kc+1) landed; set-E(kc+2) in flight
        COMPC(Ao, Bo);
        LOADC(Ao, Bo, kc + 3);
    }
    VM12;
    COMPC(Ae, Be);                  // phase 14
    VM0;
    COMPC(Ao, Bo);                  // phase 15
#undef LOADC
#undef COMPC
#undef VM12
#undef VM0

    // ---- epilogue: att -> LDS (bf16, two m-halves), GEMM2 with Wp (two q-passes, small acc2)
    float bpv[2];
#pragma unroll
    for (int cf = 0; cf < 2; ++cf) bpv[cf] = bp[cf * 32 + l31];

#pragma unroll
    for (int h = 0; h < 2; ++h) {
        __syncthreads();
#pragma unroll
        for (int q = 0; q < 2; ++q)
#pragma unroll
            for (int jj = 0; jj < 2; ++jj) {
                f32x16 a = acc[q][h * 2 + jj];
                int mloc = jj * 2 + (l31 >> 4);
                int d = l31 & 15;
#pragma unroll
                for (int r = 0; r < 16; ++r) {
                    int t = q * 32 + (r & 3) + 8 * (r >> 2) + 4 * lhi;
                    attS[(mloc * 64 + t) * 68 + w * 16 + d] = f2bf(a[r]);
                }
            }
        __syncthreads();

        int m = mt * 8 + h * 4 + w;
        size_t obase = ((size_t)(b * 190 + m) * 512 + ttile * 64) * 64;
#pragma unroll
        for (int q = 0; q < 2; ++q) {
            f32x16 acc2[2];
#pragma unroll
            for (int cf = 0; cf < 2; ++cf) acc2[cf] = (f32x16)(0.f);
#pragma unroll
            for (int kk = 0; kk < 4; ++kk) {
                bf16x8 aa = *(const bf16x8*)(attS + (w * 64 + q * 32 + l31) * 68 + kk * 16 + lhi * 8);
#pragma unroll
                for (int cf = 0; cf < 2; ++cf) {
                    bf16x8 bbf = *(const bf16x8*)(WpT + (cf * 32 + l31) * 68 + kk * 16 + lhi * 8);
                    acc2[cf] = __builtin_amdgcn_mfma_f32_32x32x16_bf16(aa, bbf, acc2[cf], 0, 0, 0);
                }
            }
            if (m < 190) {
#pragma unroll
                for (int cf = 0; cf < 2; ++cf)
#pragma unroll
                    for (int r = 0; r < 16; ++r) {
                        int t = q * 32 + (r & 3) + 8 * (r >> 2) + 4 * lhi;
                        int c = cf * 32 + l31;
                        out[obase + (size_t)t * 64 + c] = acc2[cf][r] + bpv[cf];
                    }
            }
        }
    }
}

// ----------------------------------------------------------------
extern "C" void kernel_launch(void* const* d_in, const int* in_sizes, int n_in,
                              void* d_out, int out_size, void* d_ws, size_t ws_size,
                              hipStream_t stream) {
    const float* x  = (const float*)d_in[0];
    const float* Wq = (const float*)d_in[1];
    const float* bq = (const float*)d_in[2];
    const float* Wk = (const float*)d_in[3];
    const float* bk = (const float*)d_in[4];
    const float* Wv = (const float*)d_in[5];
    const float* bv = (const float*)d_in[6];
    const float* Wp = (const float*)d_in[7];
    const float* bp = (const float*)d_in[8];

    float* out = (float*)d_out;
    float* a_out = out + (size_t)BSZ * MDIM * TDIM * CDIM;   // 24903680

    // xsum partials in the out region (8 MB), fully overwritten by k_att later.
    float* xsp = out;

    float* xsum = (float*)d_ws;                                         // 512 KB
    ushort_t* wf = (ushort_t*)((char*)d_ws + 524288);                   // 8.39 MB (4*4*16*32*512)
    ushort_t* vf = (ushort_t*)((char*)d_ws + 524288 + 8388608);         // 50.33 MB (4*24*4*32*4*512)

    k_vproj<<<512, 256, 0, stream>>>(x, Wv, bv, vf, xsp);
    k_xsum2<<<512, 256, 0, stream>>>(xsp, xsum);
    k_weights<<<256, 256, 0, stream>>>(xsum, Wq, bq, Wk, bk, wf, a_out);
    k_att<<<768, 256, 0, stream>>>(wf, vf, Wp, bp, out);
}